// Round 1
// 306.815 us; speedup vs baseline: 1.1965x; 1.1965x over previous
//
#include <hip/hip_runtime.h>

// Problem constants (reference: DIM=64, WIRES=3, INDEX=1, BATCH=128)
#define DIMQ   64
#define NCOLS  8192            // right * batch = 64*128
#define SLAB   (DIMQ * NCOLS)  // per-a complex elements = 524288
#define NA     64              // left = dim^index
#define DB     (NA * SLAB)     // D*B = 33554432

#define NT     128             // n-columns per block
#define LPITCH 72              // u16 pitch of LDS X rows (144 B, 16B-aligned, conflict-free)
#define OPITCH 132             // f32 pitch of LDS out rows (528 B, conflict-free)

typedef __attribute__((ext_vector_type(8))) __bf16 bf16x8;
typedef __attribute__((ext_vector_type(8))) unsigned short us8;
typedef __attribute__((ext_vector_type(4))) float f32x4;

__device__ __forceinline__ unsigned short f2bf(float f) {
    unsigned u = __builtin_bit_cast(unsigned, f);
    unsigned r = u + 0x7fffu + ((u >> 16) & 1u);   // RNE to bf16
    return (unsigned short)(r >> 16);
}

// ---- Variant A: output = Re(y) only, out_size = D*B float32 ----
// Block = 256 threads (4 waves). Each block: one a-slab x 128-column chunk.
// LDS-staged transpose: coalesced dwordx4 global loads -> bf16 [n][k] tile ->
// conflict-free ds_read_b128 MFMA fragments. Wave w owns i-tile w (16 rows).
__global__ __launch_bounds__(256, 4) void gate_real_kernel(
    const float* __restrict__ Mr, const float* __restrict__ Mi,
    const float* __restrict__ Xr, const float* __restrict__ Xi,
    float* __restrict__ Out)
{
    // LDS: Xr tile [128][72] u16 (18432 B) + Xi tile (18432 B) = 36864 B.
    // Out stage (64*132*4 = 33792 B) reuses the same memory after a barrier.
    __shared__ alignas(16) unsigned char smem[2 * NT * LPITCH * 2];
    unsigned short* ldsR = (unsigned short*)smem;
    unsigned short* ldsI = (unsigned short*)(smem + NT * LPITCH * 2);
    float* ldsO = (float*)smem;

    const int tid  = threadIdx.x;
    const int w    = tid >> 6;        // wave 0..3 -> i-tile
    const int lane = tid & 63;
    const int l15  = lane & 15;
    const int q    = lane >> 4;

    const int a  = blockIdx.x >> 6;
    const int n0 = (blockIdx.x & 63) * NT;
    const size_t baseA = (size_t)a * SLAB;

    // --- M fragments for this wave's i-tile (rows w*16 + l15). Negate Mi here
    //     so accR = Mr (x) Xr + (-Mi) (x) Xi needs no X-side negation. ---
    bf16x8 fMr[2], fMni[2];
#pragma unroll
    for (int kb = 0; kb < 2; ++kb) {
        const int row = w * 16 + l15;
        const int col = kb * 32 + q * 8;
        const float* pr = Mr + row * DIMQ + col;
        const float* pi = Mi + row * DIMQ + col;
        us8 hr, hni;
#pragma unroll
        for (int j = 0; j < 8; ++j) {
            hr[j]  = f2bf(pr[j]);
            hni[j] = (unsigned short)(f2bf(pi[j]) ^ 0x8000u);
        }
        fMr[kb]  = __builtin_bit_cast(bf16x8, hr);
        fMni[kb] = __builtin_bit_cast(bf16x8, hni);
    }

    // --- stage X tile (64 k x 128 n) as bf16 into LDS, transposed [n][k] ---
    // Thread: 8 k-rows x 4 n-cols. Global loads: dwordx4, each wave instr =
    // 2 rows x 512 B contiguous. LDS writes: ds_write_b128, 8 accesses/bank.
    {
        const int k0 = (tid >> 5) * 8;       // 0..56
        const int sn = (tid & 31) * 4;       // 0..124
        const float* gr = Xr + baseA + (size_t)k0 * NCOLS + n0 + sn;
        const float* gi = Xi + baseA + (size_t)k0 * NCOLS + n0 + sn;
        f32x4 vr[8], vi[8];
#pragma unroll
        for (int j = 0; j < 8; ++j)
            vr[j] = *reinterpret_cast<const f32x4*>(gr + (size_t)j * NCOLS);
#pragma unroll
        for (int j = 0; j < 8; ++j)
            vi[j] = *reinterpret_cast<const f32x4*>(gi + (size_t)j * NCOLS);
#pragma unroll
        for (int z = 0; z < 4; ++z) {
            us8 h;
#pragma unroll
            for (int j = 0; j < 8; ++j) h[j] = f2bf(vr[j][z]);
            *reinterpret_cast<us8*>(&ldsR[(sn + z) * LPITCH + k0]) = h;
        }
#pragma unroll
        for (int z = 0; z < 4; ++z) {
            us8 h;
#pragma unroll
            for (int j = 0; j < 8; ++j) h[j] = f2bf(vi[j][z]);
            *reinterpret_cast<us8*>(&ldsI[(sn + z) * LPITCH + k0]) = h;
        }
    }
    __syncthreads();

    // --- MFMA: wave w computes i-tile w (16 i) x 128 n ---
    f32x4 acc[8];
#pragma unroll
    for (int nt = 0; nt < 8; ++nt) acc[nt] = f32x4{0, 0, 0, 0};
#pragma unroll
    for (int nt = 0; nt < 8; ++nt) {
#pragma unroll
        for (int kb = 0; kb < 2; ++kb) {
            const int rbase = (nt * 16 + l15) * LPITCH + kb * 32 + q * 8;
            const bf16x8 bXr = __builtin_bit_cast(bf16x8,
                *reinterpret_cast<const us8*>(&ldsR[rbase]));
            const bf16x8 bXi = __builtin_bit_cast(bf16x8,
                *reinterpret_cast<const us8*>(&ldsI[rbase]));
            acc[nt] = __builtin_amdgcn_mfma_f32_16x16x32_bf16(fMr[kb],  bXr, acc[nt], 0, 0, 0);
            acc[nt] = __builtin_amdgcn_mfma_f32_16x16x32_bf16(fMni[kb], bXi, acc[nt], 0, 0, 0);
        }
    }
    __syncthreads();   // all fragment reads done before LDS reuse

    // --- acc -> LDS fp32 [i][n], pitch 132 floats (conflict-free) ---
    // C/D layout: col = l15, row = q*4 + r
#pragma unroll
    for (int nt = 0; nt < 8; ++nt) {
#pragma unroll
        for (int r = 0; r < 4; ++r) {
            ldsO[(w * 16 + q * 4 + r) * OPITCH + nt * 16 + l15] = acc[nt][r];
        }
    }
    __syncthreads();

    // --- coalesced dwordx4 stores: 8 rows x 512 B per pass ---
    {
        const int col = (tid & 31) * 4;
        const int r0  = tid >> 5;
#pragma unroll
        for (int p = 0; p < 8; ++p) {
            const int row = p * 8 + r0;
            const f32x4 v = *reinterpret_cast<const f32x4*>(&ldsO[row * OPITCH + col]);
            *reinterpret_cast<f32x4*>(Out + baseA + (size_t)row * NCOLS + n0 + col) = v;
        }
    }
}

// ---- Variant B (fallback): interleaved complex64 view, out_size = 2*D*B ----
// Kept as the previously-verified implementation.
__device__ __forceinline__ void load_M_frags_full(
    const float* __restrict__ Mr, const float* __restrict__ Mi,
    int l15, int q, bf16x8 fMr[4][2], bf16x8 fMi[4][2])
{
#pragma unroll
    for (int it = 0; it < 4; ++it) {
#pragma unroll
        for (int kb = 0; kb < 2; ++kb) {
            const int row = it * 16 + l15;
            const int col = kb * 32 + q * 8;
            const float* pr = Mr + row * DIMQ + col;
            const float* pi = Mi + row * DIMQ + col;
            us8 hr, hi;
#pragma unroll
            for (int j = 0; j < 8; ++j) {
                hr[j] = f2bf(pr[j]);
                hi[j] = f2bf(pi[j]);
            }
            fMr[it][kb] = __builtin_bit_cast(bf16x8, hr);
            fMi[it][kb] = __builtin_bit_cast(bf16x8, hi);
        }
    }
}

__global__ __launch_bounds__(64, 2) void gate_cplx_kernel(
    const float* __restrict__ Mr, const float* __restrict__ Mi,
    const float* __restrict__ Xr, const float* __restrict__ Xi,
    float* __restrict__ Out)
{
    const int lane = threadIdx.x;
    const int l15  = lane & 15;
    const int q    = lane >> 4;

    bf16x8 fMr[4][2], fMi[4][2];
    load_M_frags_full(Mr, Mi, l15, q, fMr, fMi);

    const int bid = blockIdx.x;
    const int a   = bid >> 6;
    const int nch = bid & 63;
    const size_t baseA = (size_t)a * SLAB;

    for (int tt = 0; tt < 8; ++tt) {
        const int n0 = nch * 128 + tt * 16;
        f32x4 accR[4] = {f32x4{0,0,0,0}, f32x4{0,0,0,0}, f32x4{0,0,0,0}, f32x4{0,0,0,0}};
        f32x4 accI[4] = {f32x4{0,0,0,0}, f32x4{0,0,0,0}, f32x4{0,0,0,0}, f32x4{0,0,0,0}};

#pragma unroll
        for (int kb = 0; kb < 2; ++kb) {
            const int krow = kb * 32 + q * 8;
            const float* pr = Xr + baseA + (size_t)krow * NCOLS + n0 + l15;
            const float* pi = Xi + baseA + (size_t)krow * NCOLS + n0 + l15;
            float fr[8], fi[8];
#pragma unroll
            for (int j = 0; j < 8; ++j) {
                fr[j] = pr[(size_t)j * NCOLS];
                fi[j] = pi[(size_t)j * NCOLS];
            }
            us8 hr, hi, hni;
#pragma unroll
            for (int j = 0; j < 8; ++j) {
                hr[j] = f2bf(fr[j]);
                const unsigned short t = f2bf(fi[j]);
                hi[j]  = t;
                hni[j] = (unsigned short)(t ^ 0x8000u);
            }
            const bf16x8 bXr  = __builtin_bit_cast(bf16x8, hr);
            const bf16x8 bXi  = __builtin_bit_cast(bf16x8, hi);
            const bf16x8 bXni = __builtin_bit_cast(bf16x8, hni);

#pragma unroll
            for (int it = 0; it < 4; ++it) {
                accR[it] = __builtin_amdgcn_mfma_f32_16x16x32_bf16(fMr[it][kb], bXr,  accR[it], 0, 0, 0);
                accR[it] = __builtin_amdgcn_mfma_f32_16x16x32_bf16(fMi[it][kb], bXni, accR[it], 0, 0, 0);
                accI[it] = __builtin_amdgcn_mfma_f32_16x16x32_bf16(fMr[it][kb], bXi,  accI[it], 0, 0, 0);
                accI[it] = __builtin_amdgcn_mfma_f32_16x16x32_bf16(fMi[it][kb], bXr,  accI[it], 0, 0, 0);
            }
        }

#pragma unroll
        for (int it = 0; it < 4; ++it) {
#pragma unroll
            for (int r = 0; r < 4; ++r) {
                const int i = it * 16 + q * 4 + r;
                const size_t cidx = baseA + (size_t)i * NCOLS + n0 + l15;
                float2 v;
                v.x = accR[it][r];
                v.y = accI[it][r];
                reinterpret_cast<float2*>(Out)[cidx] = v;
            }
        }
    }
}

extern "C" void kernel_launch(void* const* d_in, const int* in_sizes, int n_in,
                              void* d_out, int out_size, void* d_ws, size_t ws_size,
                              hipStream_t stream) {
    const float* Mr = (const float*)d_in[0];
    const float* Mi = (const float*)d_in[1];
    const float* Xr = (const float*)d_in[2];
    const float* Xi = (const float*)d_in[3];
    float* Out = (float*)d_out;

    if (out_size >= 2 * DB) {
        dim3 grid(NA * 64);
        dim3 block(64);
        gate_cplx_kernel<<<grid, block, 0, stream>>>(Mr, Mi, Xr, Xi, Out);
    } else {
        dim3 grid(NA * 64);   // 64 a-slabs * 64 column-chunks (128 cols each)
        dim3 block(256);
        gate_real_kernel<<<grid, block, 0, stream>>>(Mr, Mi, Xr, Xi, Out);
    }
}